// Round 6
// baseline (226.880 us; speedup 1.0000x reference)
//
#include <hip/hip_runtime.h>
#include <hip/hip_fp16.h>

// N = 40000 nodes, E = 640000 edges, F = 128 features, K = 2 hops.
// Bucket layout: CAP=64 slots/target node, entry = row(16b) | fp16(w)(16b).
// This round: x carried through hops as fp16 in TWO feature half-planes
// (5.12 MB each, contiguous). Blocks dispatch plane A first, then plane B,
// so the active gather working set fits the 4 MB per-XCD L2 far better
// (was 10.24 MB, ~55% miss). Same logical bytes; less L3-side traffic.

#define F   128
#define CAP 64
#define NN  40000          // nodes (compile-time for plane stride)
#define PLANE ((size_t)NN * 64)

// ---------------------------------------------------------------------------
// K0: x (fp32, [N][128]) -> xh (fp16, two planes [2][N][64]).
// thread handles feats f=2q,2q+1 of node i; plane p = q>>5.
__global__ __launch_bounds__(256) void cvt_kernel(
    const float2* __restrict__ xin, __half2* __restrict__ xh, int total) {
    int idx = blockIdx.x * 256 + threadIdx.x;   // over N*64 float2-pairs
    if (idx >= total) return;
    int i = idx >> 6, q = idx & 63;
    int p = q >> 5, qq = q & 31;
    float2 v = xin[(size_t)i * 64 + q];         // feats 2q, 2q+1
    xh[(size_t)p * (PLANE / 2) + (size_t)i * 32 + qq] = __float22half2_rn(v);
}

// ---------------------------------------------------------------------------
// K1: single-pass bucket build. 640K int atomics (only atomic pass).
__global__ void build_kernel(const int* __restrict__ ei,
                             const float* __restrict__ ew,
                             int* __restrict__ cnt,
                             unsigned int* __restrict__ bucket, int E) {
    int e = blockIdx.x * blockDim.x + threadIdx.x;
    if (e >= E) return;
    int r = ei[e];           // source (row)
    int c = ei[E + e];       // target (col)
    float w = ew[e];
    int pos = atomicAdd(&cnt[c], 1);
    if (pos < CAP) {         // P(overflow) ~ 1e-20 for Poisson(16)
        unsigned short hw = __half_as_ushort(__float2half(w));
        bucket[c * CAP + pos] = (unsigned int)r | ((unsigned int)hw << 16);
    }
}

// ---------------------------------------------------------------------------
// K2: deg (+1 self loop) and dinv per node. Wave per node, shuffle reduce.
__global__ __launch_bounds__(256) void deg_dinv_kernel(
    const unsigned int* __restrict__ bucket, const int* __restrict__ cnt,
    float* __restrict__ dinv, int N) {
    int lane = threadIdx.x & 63;
    int wid  = threadIdx.x >> 6;
    int i = blockIdx.x * 4 + wid;
    if (i >= N) return;
    int c = min(cnt[i], CAP);
    float w = 0.0f;
    if (lane < c) {
        unsigned int ent = bucket[i * CAP + lane];
        w = __half2float(__ushort_as_half((unsigned short)(ent >> 16)));
    }
    #pragma unroll
    for (int off = 32; off >= 1; off >>= 1) w += __shfl_xor(w, off, 64);
    if (lane == 0) dinv[i] = 1.0f / sqrtf(w + 1.0f);
}

// ---------------------------------------------------------------------------
// K3: one hop over ONE feature half-plane. Wave per node; lane = 1 feat
// (ushort). Blocks [0,nhalf) do plane 0, [nhalf,2*nhalf) plane 1 -- dispatch
// order gives temporal plane separation for L2 residency.
// fp32 accumulate; 8x unroll keeps 8 gathers in flight.
template <bool OUT_FP32>
__global__ __launch_bounds__(256) void hop_kernel(
    const unsigned short* __restrict__ xin, void* __restrict__ xout,
    const float* __restrict__ dinv, const unsigned int* __restrict__ bucket,
    const int* __restrict__ cnt, int nhalf) {
    int b = blockIdx.x;
    int p = (b >= nhalf) ? 1 : 0;
    if (p) b -= nhalf;
    int lane = threadIdx.x & 63;
    int wid  = threadIdx.x >> 6;
    int i = b * 4 + wid;
    const unsigned short* xp = xin + (size_t)p * PLANE;

    int c = min(cnt[i], CAP);
    float di = dinv[i];
    int r = 0; float nrm = 0.0f;
    if (lane < c) {
        unsigned int ent = bucket[i * CAP + lane];
        r = (int)(ent & 0xFFFFu);
        float w = __half2float(__ushort_as_half((unsigned short)(ent >> 16)));
        nrm = di * dinv[r] * w;
    }
    float s = __half2float(__ushort_as_half(xp[(size_t)i * 64 + lane]));
    float acc = di * di * s;                 // self-loop term
    int k = 0;
    for (; k + 8 <= c; k += 8) {
        int rr[8]; float nn[8]; unsigned short v[8];
        #pragma unroll
        for (int j = 0; j < 8; ++j) {
            rr[j] = __shfl(r, k + j);
            nn[j] = __shfl(nrm, k + j);
        }
        #pragma unroll
        for (int j = 0; j < 8; ++j) v[j] = xp[(size_t)rr[j] * 64 + lane];
        #pragma unroll
        for (int j = 0; j < 8; ++j)
            acc += nn[j] * __half2float(__ushort_as_half(v[j]));
    }
    for (; k + 4 <= c; k += 4) {
        int rr[4]; float nn[4]; unsigned short v[4];
        #pragma unroll
        for (int j = 0; j < 4; ++j) {
            rr[j] = __shfl(r, k + j);
            nn[j] = __shfl(nrm, k + j);
        }
        #pragma unroll
        for (int j = 0; j < 4; ++j) v[j] = xp[(size_t)rr[j] * 64 + lane];
        #pragma unroll
        for (int j = 0; j < 4; ++j)
            acc += nn[j] * __half2float(__ushort_as_half(v[j]));
    }
    for (; k < c; ++k) {
        int   rk = __shfl(r, k);
        float nk = __shfl(nrm, k);
        acc += nk * __half2float(__ushort_as_half(xp[(size_t)rk * 64 + lane]));
    }
    if (OUT_FP32)
        ((float*)xout)[(size_t)i * F + p * 64 + lane] = acc;         // [N][128]
    else
        ((unsigned short*)xout)[(size_t)p * PLANE + (size_t)i * 64 + lane] =
            __half_as_ushort(__float2half(acc));                     // planes
}

// ---------------------------------------------------------------------------
// K4: out[n][fo] = sum_k x2[n][k] * W[fo][k] + b[fo], in-place on d_out.
// Conflict-free k-vectorized LDS: 3 ds_read_b128 per k (round 3 fix).
__global__ __launch_bounds__(256) void linear_kernel(
    float* __restrict__ x2out, const float* __restrict__ W,
    const float* __restrict__ bias) {
    __shared__ float sX[64][68];     // [n][kk]  17.4 KB
    __shared__ float sW[128][68];    // [f][kk]  34.8 KB
    int t = threadIdx.x;
    int tx = t & 15;        // f = tx + 16*j, j = 0..7 (strided f, 2-way max)
    int ty = t >> 4;        // n = ty*4 + i, i = 0..3
    int n0 = blockIdx.x * 64;

    float acc[4][8];
    #pragma unroll
    for (int i = 0; i < 4; ++i)
        #pragma unroll
        for (int j = 0; j < 8; ++j) acc[i][j] = 0.0f;

    for (int kp = 0; kp < 2; ++kp) {
        int kbase = kp * 64;
        __syncthreads();
        #pragma unroll
        for (int it = 0; it < 4; ++it) {
            int f4 = t + 256 * it;
            int n = f4 >> 4, c4 = f4 & 15;
            float4 v = *(const float4*)&x2out[(n0 + n) * F + kbase + c4 * 4];
            *(float4*)&sX[n][c4 * 4] = v;
        }
        #pragma unroll
        for (int it = 0; it < 8; ++it) {
            int f4 = t + 256 * it;
            int f = f4 >> 4, c4 = f4 & 15;
            float4 v = *(const float4*)&W[f * F + kbase + c4 * 4];
            *(float4*)&sW[f][c4 * 4] = v;
        }
        __syncthreads();
        #pragma unroll 4
        for (int k0 = 0; k0 < 64; k0 += 4) {
            float4 a4[4], b4[8];
            #pragma unroll
            for (int i = 0; i < 4; ++i)
                a4[i] = *(const float4*)&sX[ty * 4 + i][k0];
            #pragma unroll
            for (int j = 0; j < 8; ++j)
                b4[j] = *(const float4*)&sW[tx + 16 * j][k0];
            #pragma unroll
            for (int i = 0; i < 4; ++i)
                #pragma unroll
                for (int j = 0; j < 8; ++j) {
                    acc[i][j] += a4[i].x * b4[j].x;
                    acc[i][j] += a4[i].y * b4[j].y;
                    acc[i][j] += a4[i].z * b4[j].z;
                    acc[i][j] += a4[i].w * b4[j].w;
                }
        }
    }
    #pragma unroll
    for (int i = 0; i < 4; ++i) {
        int n = n0 + ty * 4 + i;
        #pragma unroll
        for (int j = 0; j < 8; ++j)
            x2out[n * F + tx + 16 * j] = acc[i][j] + bias[tx + 16 * j];
    }
}

// ---------------------------------------------------------------------------
extern "C" void kernel_launch(void* const* d_in, const int* in_sizes, int n_in,
                              void* d_out, int out_size, void* d_ws, size_t ws_size,
                              hipStream_t stream) {
    const float* x    = (const float*)d_in[0];
    const int*   ei   = (const int*)d_in[1];     // int32 per harness contract
    const float* ew   = (const float*)d_in[2];
    const float* W    = (const float*)d_in[3];
    const float* bias = (const float*)d_in[4];
    float* out = (float*)d_out;

    const int N = in_sizes[0] / F;   // 40000
    const int E = in_sizes[2];       // 640000

    // workspace layout (256B aligned)
    char* ws = (char*)d_ws;
    size_t off = 0;
    auto take = [&](size_t bytes) {
        size_t r = off;
        off = (off + bytes + 255) & ~(size_t)255;
        return r;
    };
    size_t o_cnt    = take((size_t)N * 4);             // int, zeroed
    size_t zero_end = off;
    size_t o_dinv   = take((size_t)N * 4);             // float
    size_t o_bucket = take((size_t)N * CAP * 4);       // packed uint entries
    size_t o_xh     = take((size_t)N * F * 2);         // half, 2 planes
    size_t o_x1h    = take((size_t)N * F * 2);         // half, 2 planes
    (void)o_cnt; (void)ws_size;

    int*            cnt    = (int*)(ws);
    float*          dinv   = (float*)(ws + o_dinv);
    unsigned int*   bucket = (unsigned int*)(ws + o_bucket);
    __half2*        xh2    = (__half2*)(ws + o_xh);
    unsigned short* xh     = (unsigned short*)(ws + o_xh);
    unsigned short* x1h    = (unsigned short*)(ws + o_x1h);

    hipMemsetAsync(ws, 0, zero_end, stream);

    cvt_kernel<<<(N * 64 + 255) / 256, 256, 0, stream>>>(
        (const float2*)x, xh2, N * 64);
    build_kernel<<<(E + 255) / 256, 256, 0, stream>>>(ei, ew, cnt, bucket, E);
    deg_dinv_kernel<<<N / 4, 256, 0, stream>>>(bucket, cnt, dinv, N);
    int nhalf = N / 4;   // blocks per plane
    hop_kernel<false><<<2 * nhalf, 256, 0, stream>>>(xh, (void*)x1h,
                                                     dinv, bucket, cnt, nhalf);
    hop_kernel<true><<<2 * nhalf, 256, 0, stream>>>(x1h, (void*)out,
                                                    dinv, bucket, cnt, nhalf);
    linear_kernel<<<N / 64, 256, 0, stream>>>(out, W, bias);
}

// Round 7
// 199.810 us; speedup vs baseline: 1.1355x; 1.1355x over previous
//
#include <hip/hip_runtime.h>
#include <hip/hip_fp16.h>

// N = 40000 nodes, E = 640000 edges, F = 128 features, K = 2 hops.
// Bucket layout: CAP=64 slots/target node, entry = row(16b) | fp16(w)(16b).
// Hop design (round 7): single contiguous fp16 x plane [N][128]; HALF-WAVE
// (32 lanes) per node, lane = 4 feats = 8 B -> one global_load_dwordx2 moves
// 512 B/wave (2 edges, one per half-wave). __shfl(width=32) broadcasts each
// half's own bucket entry in one instruction. Round-6 lesson: this gather is
// request-rate bound, so maximize bytes per instruction and bytes in flight.

#define F   128
#define CAP 64

// ---------------------------------------------------------------------------
// K0: x (fp32, [N][128]) -> xh (fp16, [N][128]). float2 -> half2 per thread.
__global__ __launch_bounds__(256) void cvt_kernel(
    const float2* __restrict__ xin, __half2* __restrict__ xh, int total) {
    int idx = blockIdx.x * 256 + threadIdx.x;   // over N*64 pairs
    if (idx >= total) return;
    xh[idx] = __float22half2_rn(xin[idx]);
}

// ---------------------------------------------------------------------------
// K1: single-pass bucket build. 640K int atomics (only atomic pass).
__global__ void build_kernel(const int* __restrict__ ei,
                             const float* __restrict__ ew,
                             int* __restrict__ cnt,
                             unsigned int* __restrict__ bucket, int E) {
    int e = blockIdx.x * blockDim.x + threadIdx.x;
    if (e >= E) return;
    int r = ei[e];           // source (row)
    int c = ei[E + e];       // target (col)
    float w = ew[e];
    int pos = atomicAdd(&cnt[c], 1);
    if (pos < CAP) {         // P(overflow) ~ 1e-20 for Poisson(16)
        unsigned short hw = __half_as_ushort(__float2half(w));
        bucket[c * CAP + pos] = (unsigned int)r | ((unsigned int)hw << 16);
    }
}

// ---------------------------------------------------------------------------
// K2: deg (+1 self loop) and dinv per node. Wave per node, shuffle reduce.
__global__ __launch_bounds__(256) void deg_dinv_kernel(
    const unsigned int* __restrict__ bucket, const int* __restrict__ cnt,
    float* __restrict__ dinv, int N) {
    int lane = threadIdx.x & 63;
    int wid  = threadIdx.x >> 6;
    int i = blockIdx.x * 4 + wid;
    if (i >= N) return;
    int c = min(cnt[i], CAP);
    float w = 0.0f;
    if (lane < c) {
        unsigned int ent = bucket[i * CAP + lane];
        w = __half2float(__ushort_as_half((unsigned short)(ent >> 16)));
    }
    #pragma unroll
    for (int off = 32; off >= 1; off >>= 1) w += __shfl_xor(w, off, 64);
    if (lane == 0) dinv[i] = 1.0f / sqrtf(w + 1.0f);
}

// ---------------------------------------------------------------------------
// K3: one hop. Half-wave per node: q = lane&31 covers feats 4q..4q+3.
// Entries q and q+32 preloaded; invalid lanes carry nrm=0, row=self.
// k-loop is wave-uniform to cmax = max(c_half0, c_half1); stage 1 uses
// entry set 0 (k<32), stage 2 set 1. 8x unroll = 4 KB in flight per wave.
template <bool OUT_FP32>
__global__ __launch_bounds__(256) void hop_kernel(
    const unsigned short* __restrict__ xin, void* __restrict__ xout,
    const float* __restrict__ dinv, const unsigned int* __restrict__ bucket,
    const int* __restrict__ cnt) {
    int t = threadIdx.x;
    int lane = t & 63;
    int wid  = t >> 6;
    int q = lane & 31;                       // lane within half-wave
    int h = lane >> 5;                       // which half
    int i = blockIdx.x * 8 + wid * 2 + h;    // node for this half-wave

    int c = min(cnt[i], CAP);
    float di = dinv[i];
    int r0 = i, r1 = i;
    float n0 = 0.0f, n1 = 0.0f;
    if (q < c) {
        unsigned int ent = bucket[i * CAP + q];
        r0 = (int)(ent & 0xFFFFu);
        float w = __half2float(__ushort_as_half((unsigned short)(ent >> 16)));
        n0 = di * dinv[r0] * w;
    }
    if (q + 32 < c) {
        unsigned int ent = bucket[i * CAP + q + 32];
        r1 = (int)(ent & 0xFFFFu);
        float w = __half2float(__ushort_as_half((unsigned short)(ent >> 16)));
        n1 = di * dinv[r1] * w;
    }
    int cmax = max(c, __shfl_xor(c, 32, 64));   // wave-uniform loop bound

    // self-loop term
    uint2 sv = *(const uint2*)(xin + (size_t)i * F + q * 4);
    float2 slo = __half22float2(*(const __half2*)&sv.x);
    float2 shi = __half22float2(*(const __half2*)&sv.y);
    float dii = di * di;
    float4 acc = make_float4(dii * slo.x, dii * slo.y, dii * shi.x, dii * shi.y);

    int kend1 = cmax < 32 ? cmax : 32;
    int k = 0;
    for (; k + 8 <= kend1; k += 8) {
        int rr[8]; float nn[8]; uint2 v[8];
        #pragma unroll
        for (int j = 0; j < 8; ++j) {
            rr[j] = __shfl(r0, k + j, 32);
            nn[j] = __shfl(n0, k + j, 32);
        }
        #pragma unroll
        for (int j = 0; j < 8; ++j)
            v[j] = *(const uint2*)(xin + (size_t)rr[j] * F + q * 4);
        #pragma unroll
        for (int j = 0; j < 8; ++j) {
            float2 lo = __half22float2(*(const __half2*)&v[j].x);
            float2 hi = __half22float2(*(const __half2*)&v[j].y);
            acc.x += nn[j] * lo.x; acc.y += nn[j] * lo.y;
            acc.z += nn[j] * hi.x; acc.w += nn[j] * hi.y;
        }
    }
    for (; k < kend1; ++k) {
        int   rk = __shfl(r0, k, 32);
        float nk = __shfl(n0, k, 32);
        uint2 v  = *(const uint2*)(xin + (size_t)rk * F + q * 4);
        float2 lo = __half22float2(*(const __half2*)&v.x);
        float2 hi = __half22float2(*(const __half2*)&v.y);
        acc.x += nk * lo.x; acc.y += nk * lo.y;
        acc.z += nk * hi.x; acc.w += nk * hi.y;
    }
    // stage 2: entries 32..cmax
    for (; k + 8 <= cmax; k += 8) {
        int rr[8]; float nn[8]; uint2 v[8];
        #pragma unroll
        for (int j = 0; j < 8; ++j) {
            rr[j] = __shfl(r1, k - 32 + j, 32);
            nn[j] = __shfl(n1, k - 32 + j, 32);
        }
        #pragma unroll
        for (int j = 0; j < 8; ++j)
            v[j] = *(const uint2*)(xin + (size_t)rr[j] * F + q * 4);
        #pragma unroll
        for (int j = 0; j < 8; ++j) {
            float2 lo = __half22float2(*(const __half2*)&v[j].x);
            float2 hi = __half22float2(*(const __half2*)&v[j].y);
            acc.x += nn[j] * lo.x; acc.y += nn[j] * lo.y;
            acc.z += nn[j] * hi.x; acc.w += nn[j] * hi.y;
        }
    }
    for (; k < cmax; ++k) {
        int   rk = __shfl(r1, k - 32, 32);
        float nk = __shfl(n1, k - 32, 32);
        uint2 v  = *(const uint2*)(xin + (size_t)rk * F + q * 4);
        float2 lo = __half22float2(*(const __half2*)&v.x);
        float2 hi = __half22float2(*(const __half2*)&v.y);
        acc.x += nk * lo.x; acc.y += nk * lo.y;
        acc.z += nk * hi.x; acc.w += nk * hi.y;
    }

    if (OUT_FP32) {
        *(float4*)&((float*)xout)[(size_t)i * F + q * 4] = acc;
    } else {
        uint2 o;
        *(__half2*)&o.x = __float22half2_rn(make_float2(acc.x, acc.y));
        *(__half2*)&o.y = __float22half2_rn(make_float2(acc.z, acc.w));
        *(uint2*)&((unsigned short*)xout)[(size_t)i * F + q * 4] = o;
    }
}

// ---------------------------------------------------------------------------
// K4: out[n][fo] = sum_k x2[n][k] * W[fo][k] + b[fo], in-place on d_out.
// Conflict-free k-vectorized LDS: 3 ds_read_b128 per k (round 3 fix).
__global__ __launch_bounds__(256) void linear_kernel(
    float* __restrict__ x2out, const float* __restrict__ W,
    const float* __restrict__ bias) {
    __shared__ float sX[64][68];     // [n][kk]  17.4 KB
    __shared__ float sW[128][68];    // [f][kk]  34.8 KB
    int t = threadIdx.x;
    int tx = t & 15;        // f = tx + 16*j, j = 0..7 (strided f, 2-way max)
    int ty = t >> 4;        // n = ty*4 + i, i = 0..3
    int n0 = blockIdx.x * 64;

    float acc[4][8];
    #pragma unroll
    for (int i = 0; i < 4; ++i)
        #pragma unroll
        for (int j = 0; j < 8; ++j) acc[i][j] = 0.0f;

    for (int kp = 0; kp < 2; ++kp) {
        int kbase = kp * 64;
        __syncthreads();
        #pragma unroll
        for (int it = 0; it < 4; ++it) {
            int f4 = t + 256 * it;
            int n = f4 >> 4, c4 = f4 & 15;
            float4 v = *(const float4*)&x2out[(n0 + n) * F + kbase + c4 * 4];
            *(float4*)&sX[n][c4 * 4] = v;
        }
        #pragma unroll
        for (int it = 0; it < 8; ++it) {
            int f4 = t + 256 * it;
            int f = f4 >> 4, c4 = f4 & 15;
            float4 v = *(const float4*)&W[f * F + kbase + c4 * 4];
            *(float4*)&sW[f][c4 * 4] = v;
        }
        __syncthreads();
        #pragma unroll 4
        for (int k0 = 0; k0 < 64; k0 += 4) {
            float4 a4[4], b4[8];
            #pragma unroll
            for (int i = 0; i < 4; ++i)
                a4[i] = *(const float4*)&sX[ty * 4 + i][k0];
            #pragma unroll
            for (int j = 0; j < 8; ++j)
                b4[j] = *(const float4*)&sW[tx + 16 * j][k0];
            #pragma unroll
            for (int i = 0; i < 4; ++i)
                #pragma unroll
                for (int j = 0; j < 8; ++j) {
                    acc[i][j] += a4[i].x * b4[j].x;
                    acc[i][j] += a4[i].y * b4[j].y;
                    acc[i][j] += a4[i].z * b4[j].z;
                    acc[i][j] += a4[i].w * b4[j].w;
                }
        }
    }
    #pragma unroll
    for (int i = 0; i < 4; ++i) {
        int n = n0 + ty * 4 + i;
        #pragma unroll
        for (int j = 0; j < 8; ++j)
            x2out[n * F + tx + 16 * j] = acc[i][j] + bias[tx + 16 * j];
    }
}

// ---------------------------------------------------------------------------
extern "C" void kernel_launch(void* const* d_in, const int* in_sizes, int n_in,
                              void* d_out, int out_size, void* d_ws, size_t ws_size,
                              hipStream_t stream) {
    const float* x    = (const float*)d_in[0];
    const int*   ei   = (const int*)d_in[1];     // int32 per harness contract
    const float* ew   = (const float*)d_in[2];
    const float* W    = (const float*)d_in[3];
    const float* bias = (const float*)d_in[4];
    float* out = (float*)d_out;

    const int N = in_sizes[0] / F;   // 40000
    const int E = in_sizes[2];       // 640000

    // workspace layout (256B aligned)
    char* ws = (char*)d_ws;
    size_t off = 0;
    auto take = [&](size_t bytes) {
        size_t r = off;
        off = (off + bytes + 255) & ~(size_t)255;
        return r;
    };
    size_t o_cnt    = take((size_t)N * 4);             // int, zeroed
    size_t zero_end = off;
    size_t o_dinv   = take((size_t)N * 4);             // float
    size_t o_bucket = take((size_t)N * CAP * 4);       // packed uint entries
    size_t o_xh     = take((size_t)N * F * 2);         // half [N][128]
    size_t o_x1h    = take((size_t)N * F * 2);         // half [N][128]
    (void)o_cnt; (void)ws_size;

    int*            cnt    = (int*)(ws);
    float*          dinv   = (float*)(ws + o_dinv);
    unsigned int*   bucket = (unsigned int*)(ws + o_bucket);
    __half2*        xh2    = (__half2*)(ws + o_xh);
    unsigned short* xh     = (unsigned short*)(ws + o_xh);
    unsigned short* x1h    = (unsigned short*)(ws + o_x1h);

    hipMemsetAsync(ws, 0, zero_end, stream);

    cvt_kernel<<<(N * 64 + 255) / 256, 256, 0, stream>>>(
        (const float2*)x, xh2, N * 64);
    build_kernel<<<(E + 255) / 256, 256, 0, stream>>>(ei, ew, cnt, bucket, E);
    deg_dinv_kernel<<<N / 4, 256, 0, stream>>>(bucket, cnt, dinv, N);
    hop_kernel<false><<<N / 8, 256, 0, stream>>>(xh, (void*)x1h,
                                                 dinv, bucket, cnt);
    hop_kernel<true><<<N / 8, 256, 0, stream>>>(x1h, (void*)out,
                                                dinv, bucket, cnt);
    linear_kernel<<<N / 64, 256, 0, stream>>>(out, W, bias);
}